// Round 10
// baseline (602.746 us; speedup 1.0000x reference)
//
#include <hip/hip_runtime.h>
#include <hip/hip_bf16.h>
#include <stdint.h>

typedef __bf16 bf16_t;
typedef bf16_t bf16x8 __attribute__((ext_vector_type(8)));
typedef bf16_t bf16x4 __attribute__((ext_vector_type(4)));
typedef float  f32x4  __attribute__((ext_vector_type(4)));

#define B_DIM 16384

// fenced barrier: reads/stages may not cross (they must issue pre-barrier)
#define BARM()   do { asm volatile("" ::: "memory"); \
                      __builtin_amdgcn_s_barrier();  \
                      asm volatile("" ::: "memory"); } while (0)
#define MEMF()   asm volatile("" ::: "memory")
#define VMCNT6() asm volatile("s_waitcnt vmcnt(6)" ::: "memory")
#define VMCNT0() asm volatile("s_waitcnt vmcnt(0)" ::: "memory")

// async global->LDS, 16B per lane; LDS dest is wave-uniform base (+lane*16 by HW)
__device__ __forceinline__ void async_copy16(void* lptr, const void* gptr) {
  __builtin_amdgcn_global_load_lds(
      (const __attribute__((address_space(1))) unsigned int*)gptr,
      (__attribute__((address_space(3))) unsigned int*)lptr, 16, 0, 0);
}

// ---------------- cast x + w1 + w2 fp32 -> bf16 ----------------
__global__ void cast_all_kernel(const float* __restrict__ x, const float* __restrict__ w1,
                                const float* __restrict__ w2, bf16_t* __restrict__ xb,
                                bf16_t* __restrict__ w1b, bf16_t* __restrict__ w2b) {
  size_t c = (size_t)blockIdx.x * 256 + threadIdx.x;  // 8-elem chunk id
  const float* s; bf16_t* d; size_t off;
  if (c < 8388608)      { s = x;  d = xb;  off = c; }            // 16384*4096/8
  else if (c < 8912896) { s = w1; d = w1b; off = c - 8388608; }  // 4*1024*1024/8
  else                  { s = w2; d = w2b; off = c - 8912896; }
  size_t i = off * 8;
  f32x4 a = *(const f32x4*)(s + i);
  f32x4 b = *(const f32x4*)(s + i + 4);
  bf16x8 o;
  o[0]=(bf16_t)a[0]; o[1]=(bf16_t)a[1]; o[2]=(bf16_t)a[2]; o[3]=(bf16_t)a[3];
  o[4]=(bf16_t)b[0]; o[5]=(bf16_t)b[1]; o[6]=(bf16_t)b[2]; o[7]=(bf16_t)b[3];
  *(bf16x8*)(d + i) = o;
}

// ============ 256x256 8-phase GEMM (BK=64, 8 waves, 16x16x32 bf16) ============
// SINGLE-BARRIER phases (R9, verified): [reads(P); stage; (vmcnt); BAR; MFMA(P)].
// EPI 0: P1-scatter -> inter[b*4096 + l*1024 + r]   (GEMM1; zi-slowest mapping)
// EPI 1: FUSED P2+bias -> out[b, s*4+l] fp32        (GEMM2; zi-FASTEST mapping
//        so the 4 zi-partner blocks of a (mt,nt) tile are L2-co-resident and
//        their 16B/64B-line partial writes merge before HBM eviction)
template<int EPI>
__global__ __launch_bounds__(512, 2)
void monarch_gemm8(const bf16_t* __restrict__ Ab, const bf16_t* __restrict__ Wb,
                   bf16_t* __restrict__ Outb, float* __restrict__ Outf,
                   const float* __restrict__ bias)
{
  __shared__ __align__(16) char smem[131072];
  const int tid  = threadIdx.x;
  const int lane = tid & 63;
  const int wid  = tid >> 6;
  const int wm   = wid >> 2;       // 2 (M) x 4 (N) wave grid; wave tile 128x64
  const int wn   = wid & 3;

  // XCD-chunked swizzle: 1024 blocks, 128 consecutive logicals per XCD
  const int pb = blockIdx.x;
  const int lb = (pb & 7) * 128 + (pb >> 3);
  int zi, mt, nt;
  if (EPI == 0) { zi = lb >> 8;  mt = (lb & 255) >> 2; nt = lb & 3; }
  else          { zi = lb & 3;   nt = (lb >> 2) & 3;   mt = lb >> 4; }

  const size_t brow0 = (size_t)mt * 256;
  const int    ncol0 = nt * 256;

  const bf16_t* Asrc = Ab + brow0 * 4096 + (size_t)zi * 1024;          // stride 4096
  const bf16_t* Bsrc = Wb + ((size_t)zi << 20) + (size_t)ncol0 * 1024; // stride 1024

  // staging source swizzle (T2): linear LDS chunk c' holds source chunk c'^(row&7)
  const int sRow = lane >> 3;
  const int sC   = (lane & 7) ^ sRow;

// stage half H (0=A0,1=A1,2=B0,3=B1) of K-tile T into buffer BUF (literals!)
#define STAGE(BUF, T, H) do {                                                   \
    const bf16_t* _s = (H) < 2 ? Asrc + ((size_t)((H) * 128) * 4096) + (T) * 64 \
                               : Bsrc + ((size_t)(((H)-2) * 128) * 1024) + (T) * 64; \
    const size_t _st = (H) < 2 ? 4096 : 1024;                                   \
    async_copy16(smem + (BUF)*65536 + ((H)>>1)*32768 + ((H)&1)*16384 + wid*1024,\
                 _s + (size_t)(wid * 8 + sRow) * _st + sC * 8);                 \
    async_copy16(smem + (BUF)*65536 + ((H)>>1)*32768 + ((H)&1)*16384 + 8192 + wid*1024, \
                 _s + (size_t)(64 + wid * 8 + sRow) * _st + sC * 8);            \
  } while (0)

  // ds_read addressing (swizzled): chunk c0 read at linear c0^(lane&7)
  const int cs0 = ((0 + (lane >> 4)) ^ (lane & 7)) * 16;   // kk=0
  const int cs1 = ((4 + (lane >> 4)) ^ (lane & 7)) * 16;   // kk=1
  const int aBase = (wm * 128 + (lane & 15)) * 128;
  const int bBase = 32768 + (wn * 64 + (lane & 15)) * 128;

#define RDA(buf, m, kk) (*(const bf16x8*)(smem + (buf)*65536 + aBase + (m)*2048 + ((kk)?cs1:cs0)))
#define RDB(buf, n, kk) (*(const bf16x8*)(smem + (buf)*65536 + bBase + (n)*2048 + ((kk)?cs1:cs0)))

  f32x4 acc[8][4] = {};
  bf16x8 aM0[4][2], aM1[4][2], bN0[2][2], bN1[2][2];

#define MFMA_QUAD(AR, Aarr, NB, Barr)                                              \
  __builtin_amdgcn_s_setprio(1);                                                   \
  _Pragma("unroll") for (int m = 0; m < 4; ++m)                                    \
  _Pragma("unroll") for (int n = 0; n < 2; ++n)                                    \
  _Pragma("unroll") for (int kk = 0; kk < 2; ++kk)                                 \
    acc[(AR)+m][(NB)+n] = __builtin_amdgcn_mfma_f32_16x16x32_bf16(                 \
        Aarr[m][kk], Barr[n][kk], acc[(AR)+m][(NB)+n], 0, 0, 0);                   \
  __builtin_amdgcn_s_setprio(0);

#define LD_A0(buf) _Pragma("unroll") for (int m = 0; m < 4; ++m) { \
    aM0[m][0] = RDA(buf,m,0); aM0[m][1] = RDA(buf,m,1); }
#define LD_A1(buf) _Pragma("unroll") for (int m = 0; m < 4; ++m) { \
    aM1[m][0] = RDA(buf,m+4,0); aM1[m][1] = RDA(buf,m+4,1); }
#define LD_B0(buf) _Pragma("unroll") for (int n = 0; n < 2; ++n) { \
    bN0[n][0] = RDB(buf,n,0); bN0[n][1] = RDB(buf,n,1); }
#define LD_B1(buf) _Pragma("unroll") for (int n = 0; n < 2; ++n) { \
    bN1[n][0] = RDB(buf,n+2,0); bN1[n][1] = RDB(buf,n+2,1); }

  // ---- prologue: T0 (4 halves, buf0) + T1 (A0,A1,B0, buf1); strict order ----
  STAGE(0,0,0); MEMF(); STAGE(0,0,1); MEMF(); STAGE(0,0,2); MEMF(); STAGE(0,0,3); MEMF();
  STAGE(1,1,0); MEMF(); STAGE(1,1,1); MEMF(); STAGE(1,1,2);
  VMCNT6(); BARM();    // T0's 8 loads landed -> buf0 ready; 6 in flight

  for (int it2 = 0; it2 < 8; ++it2) {
    const int t0 = it2 * 2;
    const bool nl = (it2 < 7);
    // ---- P1: rd aM0,bN0(buf0) ; MFMA M0N0 ----
    LD_A0(0); LD_B0(0);
    MEMF(); STAGE(1, t0+1, 3);
    BARM();
    MFMA_QUAD(0, aM0, 0, bN0);
    // ---- P2: rd aM1(buf0) ; MFMA M1N0 ----
    LD_A1(0);
    BARM();
    MFMA_QUAD(4, aM1, 0, bN0);
    // ---- P3: rd bN1(buf0) ; MFMA M0N1 ----
    LD_B1(0);
    if (nl) { MEMF(); STAGE(0, t0+2, 0); }
    BARM();
    MFMA_QUAD(0, aM0, 2, bN1);
    // ---- P4: publish buf1(t0+1) ; MFMA M1N1 ----
    if (nl) { MEMF(); STAGE(0, t0+2, 1); MEMF(); STAGE(0, t0+2, 2); VMCNT6(); }
    else    { VMCNT0(); }
    BARM();
    MFMA_QUAD(4, aM1, 2, bN1);
    // ---- P5: rd aM0,bN0(buf1) ; MFMA M0N0 ----
    LD_A0(1); LD_B0(1);
    if (nl) { MEMF(); STAGE(0, t0+2, 3); }
    BARM();
    MFMA_QUAD(0, aM0, 0, bN0);
    // ---- P6: rd aM1(buf1) ; MFMA M1N0 ----
    LD_A1(1);
    BARM();
    MFMA_QUAD(4, aM1, 0, bN0);
    // ---- P7: rd bN1(buf1) ; MFMA M0N1 ----
    LD_B1(1);
    if (nl) { MEMF(); STAGE(1, t0+3, 0); }
    BARM();
    MFMA_QUAD(0, aM0, 2, bN1);
    // ---- P8: publish buf0(t0+2) ; MFMA M1N1 ----
    if (nl) { MEMF(); STAGE(1, t0+3, 1); MEMF(); STAGE(1, t0+3, 2); VMCNT6(); }
    BARM();
    MFMA_QUAD(4, aM1, 2, bN1);
  }

  // ---- epilogue: two 128-row halves through LDS (vmcnt drained at it7 P4) ----
  if (EPI == 0) {
    // layout [128][4][72]: row*288 + l*72 + rv
    bf16_t* C0 = (bf16_t*)smem;
    #pragma unroll
    for (int half = 0; half < 2; ++half) {
      BARM();
      if (wm == half) {
        const int rg = lane >> 4, cl = lane & 15;
        const int l = cl & 3, rvb = cl >> 2;
        #pragma unroll
        for (int m = 0; m < 8; ++m)
          #pragma unroll
          for (int n = 0; n < 4; ++n) {
            const int rowb = (m * 16 + rg * 4) * 288 + l * 72 + wn * 16 + n * 4 + rvb;
            #pragma unroll
            for (int j = 0; j < 4; ++j)
              C0[rowb + j * 288] = (bf16_t)acc[m][n][j];
          }
      }
      BARM();
      #pragma unroll
      for (int i = 0; i < 8; ++i) {
        const int s = i * 512 + tid;            // 4096 16B segments
        const int row = s >> 5, l2 = (s >> 3) & 3, part = s & 7;
        bf16x8 v = *(const bf16x8*)&C0[row * 288 + l2 * 72 + part * 8];
        *(bf16x8*)&Outb[(brow0 + half * 128 + row) * 4096 +
                        l2 * 1024 + zi * 256 + nt * 64 + part * 8] = v;
      }
    }
  } else {
    // FUSED P2 + bias: out[b, (ncol0+col)*4 + zi] = C[row][col] + bias[...]
    bf16_t* C = (bf16_t*)smem;                       // [128][264] = 67584 B
    float*  biasLds = (float*)(smem + 69632);        // 256 floats (our zi slice)
    #pragma unroll
    for (int half = 0; half < 2; ++half) {
      BARM();
      if (wm == half) {
        const int rg = lane >> 4, cl = lane & 15;
        #pragma unroll
        for (int m = 0; m < 8; ++m)
          #pragma unroll
          for (int n = 0; n < 4; ++n) {
            const int rl = m * 16 + rg * 4;
            const int col = wn * 64 + n * 16 + cl;
            #pragma unroll
            for (int j = 0; j < 4; ++j)
              C[(rl + j) * 264 + col] = (bf16_t)acc[m][n][j];
          }
      }
      if (half == 0 && tid < 256)
        biasLds[tid] = bias[(size_t)(ncol0 + tid) * 4 + zi];
      BARM();
      #pragma unroll
      for (int i = 0; i < 8; ++i) {
        const int c = i * 512 + tid;                 // 4096 chunks of 8 elems
        const int row = c >> 5, ch = c & 31;
        bf16x8 v = *(const bf16x8*)&C[row * 264 + ch * 8];
        f32x4 b0 = *(const f32x4*)&biasLds[ch * 8];
        f32x4 b1 = *(const f32x4*)&biasLds[ch * 8 + 4];
        const size_t rowOff = (brow0 + half * 128 + row) * 4096;
        const size_t sbase  = (size_t)(ncol0 + ch * 8) * 4 + zi;
        #pragma unroll
        for (int u = 0; u < 4; ++u)
          Outf[rowOff + sbase + u * 4] = (float)v[u] + b0[u];
        #pragma unroll
        for (int u = 0; u < 4; ++u)
          Outf[rowOff + sbase + (u + 4) * 4] = (float)v[u + 4] + b1[u];
      }
    }
  }
#undef RDA
#undef RDB
#undef MFMA_QUAD
#undef LD_A0
#undef LD_A1
#undef LD_B0
#undef LD_B1
#undef STAGE
}

extern "C" void kernel_launch(void* const* d_in, const int* in_sizes, int n_in,
                              void* d_out, int out_size, void* d_ws, size_t ws_size,
                              hipStream_t stream) {
  const float* x    = (const float*)d_in[0];
  const float* w1   = (const float*)d_in[1];
  const float* w2   = (const float*)d_in[2];
  const float* bias = (const float*)d_in[3];
  float* out = (float*)d_out;

  char* ws = (char*)d_ws;
  const size_t xbBytes    = (size_t)B_DIM * 4096 * 2;   // 134 MB
  const size_t wBytes     = (size_t)8 << 20;            // per w array (bf16)
  bf16_t* xb    = (bf16_t*)(ws);
  bf16_t* w1b   = (bf16_t*)(ws + xbBytes);
  bf16_t* w2b   = (bf16_t*)(ws + xbBytes + wBytes);
  bf16_t* inter = (bf16_t*)(ws + xbBytes + 2 * wBytes);

  cast_all_kernel<<<36864, 256, 0, stream>>>(x, w1, w2, xb, w1b, w2b);
  monarch_gemm8<0><<<1024, 512, 0, stream>>>(xb, w1b, inter, nullptr, nullptr);
  monarch_gemm8<1><<<1024, 512, 0, stream>>>(inter, w2b, nullptr, out, bias);
}

// Round 11
// 506.906 us; speedup vs baseline: 1.1891x; 1.1891x over previous
//
#include <hip/hip_runtime.h>
#include <hip/hip_bf16.h>
#include <stdint.h>

typedef __bf16 bf16_t;
typedef bf16_t bf16x8 __attribute__((ext_vector_type(8)));
typedef bf16_t bf16x4 __attribute__((ext_vector_type(4)));
typedef float  f32x4  __attribute__((ext_vector_type(4)));
typedef float  f32x16 __attribute__((ext_vector_type(16)));

#define B_DIM 16384

// fenced barrier: reads/stages may not cross (they must issue pre-barrier)
#define BARM()   do { asm volatile("" ::: "memory"); \
                      __builtin_amdgcn_s_barrier();  \
                      asm volatile("" ::: "memory"); } while (0)
#define MEMF()   asm volatile("" ::: "memory")
#define VMCNT6() asm volatile("s_waitcnt vmcnt(6)" ::: "memory")
#define VMCNT0() asm volatile("s_waitcnt vmcnt(0)" ::: "memory")

// async global->LDS, 16B per lane; LDS dest is wave-uniform base (+lane*16 by HW)
__device__ __forceinline__ void async_copy16(void* lptr, const void* gptr) {
  __builtin_amdgcn_global_load_lds(
      (const __attribute__((address_space(1))) unsigned int*)gptr,
      (__attribute__((address_space(3))) unsigned int*)lptr, 16, 0, 0);
}

// ---------------- cast x + w1 + w2 fp32 -> bf16 ----------------
__global__ void cast_all_kernel(const float* __restrict__ x, const float* __restrict__ w1,
                                const float* __restrict__ w2, bf16_t* __restrict__ xb,
                                bf16_t* __restrict__ w1b, bf16_t* __restrict__ w2b) {
  size_t c = (size_t)blockIdx.x * 256 + threadIdx.x;  // 8-elem chunk id
  const float* s; bf16_t* d; size_t off;
  if (c < 8388608)      { s = x;  d = xb;  off = c; }            // 16384*4096/8
  else if (c < 8912896) { s = w1; d = w1b; off = c - 8388608; }  // 4*1024*1024/8
  else                  { s = w2; d = w2b; off = c - 8912896; }
  size_t i = off * 8;
  f32x4 a = *(const f32x4*)(s + i);
  f32x4 b = *(const f32x4*)(s + i + 4);
  bf16x8 o;
  o[0]=(bf16_t)a[0]; o[1]=(bf16_t)a[1]; o[2]=(bf16_t)a[2]; o[3]=(bf16_t)a[3];
  o[4]=(bf16_t)b[0]; o[5]=(bf16_t)b[1]; o[6]=(bf16_t)b[2]; o[7]=(bf16_t)b[3];
  *(bf16x8*)(d + i) = o;
}

// ============ 256x256 8-phase GEMM (BK=64, 8 waves, 32x32x16 bf16) ============
// R9's proven SINGLE-BARRIER schedule: [reads(P); stage; (vmcnt); BAR; MFMA(P)].
// MFMA switched 16x16x32 -> 32x32x16 (m06: 2382 vs 2075 TF; 8 instrs/phase vs
// 16). LDS layout, swizzle, ledger, read counts per phase all UNCHANGED.
// C/D layout (m74/m101 verified): col=lane&31, row=(reg&3)+8*(reg>>2)+4*(lane>>5).
// EPI 0: P1-scatter -> inter[b*4096 + l*1024 + r]      (GEMM1)
// EPI 1: contiguous -> o2[b*4096 + zi*1024 + s]        (GEMM2)
template<int EPI>
__global__ __launch_bounds__(512, 2)
void monarch_gemm8(const bf16_t* __restrict__ Ab, const bf16_t* __restrict__ Wb,
                   bf16_t* __restrict__ Outb)
{
  __shared__ __align__(16) char smem[131072];
  const int tid  = threadIdx.x;
  const int lane = tid & 63;
  const int wid  = tid >> 6;
  const int wm   = wid >> 2;       // 2 (M) x 4 (N) wave grid; wave tile 128x64
  const int wn   = wid & 3;

  // XCD-chunked swizzle: 1024 blocks, 128 consecutive logicals per XCD
  const int pb = blockIdx.x;
  const int lb = (pb & 7) * 128 + (pb >> 3);
  const int zi = lb >> 8;                  // k (GEMM1) or l (GEMM2)
  const int mt = (lb & 255) >> 2;          // 64 M-tiles
  const int nt = lb & 3;                   // 4 N-tiles

  const size_t brow0 = (size_t)mt * 256;
  const int    ncol0 = nt * 256;

  const bf16_t* Asrc = Ab + brow0 * 4096 + (size_t)zi * 1024;          // stride 4096
  const bf16_t* Bsrc = Wb + ((size_t)zi << 20) + (size_t)ncol0 * 1024; // stride 1024

  // staging source swizzle (T2): linear LDS chunk c' holds source chunk c'^(row&7)
  const int sRow = lane >> 3;
  const int sC   = (lane & 7) ^ sRow;

// stage half H (0=A0,1=A1,2=B0,3=B1) of K-tile T into buffer BUF (literals!)
#define STAGE(BUF, T, H) do {                                                   \
    const bf16_t* _s = (H) < 2 ? Asrc + ((size_t)((H) * 128) * 4096) + (T) * 64 \
                               : Bsrc + ((size_t)(((H)-2) * 128) * 1024) + (T) * 64; \
    const size_t _st = (H) < 2 ? 4096 : 1024;                                   \
    async_copy16(smem + (BUF)*65536 + ((H)>>1)*32768 + ((H)&1)*16384 + wid*1024,\
                 _s + (size_t)(wid * 8 + sRow) * _st + sC * 8);                 \
    async_copy16(smem + (BUF)*65536 + ((H)>>1)*32768 + ((H)&1)*16384 + 8192 + wid*1024, \
                 _s + (size_t)(64 + wid * 8 + sRow) * _st + sC * 8);            \
  } while (0)

  // ds_read addressing (swizzled): chunk c read at linear c^(lane&7).
  // 32x32x16 A/B operand: row = base + (lane&31); chunk = k16*2 + (lane>>5).
  const int l31 = lane & 31;
  const int l7  = lane & 7;
  const int hi  = lane >> 5;               // 0..1

#define RDA32(buf, mb, k16) (*(const bf16x8*)(smem + (buf)*65536 + \
    (wm*128 + (mb)*32 + l31) * 128 + ((((k16)*2 + hi) ^ l7) * 16)))
#define RDB32(buf, nb, k16) (*(const bf16x8*)(smem + (buf)*65536 + 32768 + \
    (wn*64 + (nb)*32 + l31) * 128 + ((((k16)*2 + hi) ^ l7) * 16)))

  f32x16 acc[4][2] = {};                   // [mb 0..3][nb 0..1]
  bf16x8 aM0[2][4], aM1[2][4], bN0[4], bN1[4];

#define MFMA_QUAD(MB, Aarr, NB, Barr)                                              \
  __builtin_amdgcn_s_setprio(1);                                                   \
  _Pragma("unroll") for (int mb = 0; mb < 2; ++mb)                                 \
  _Pragma("unroll") for (int k16 = 0; k16 < 4; ++k16)                              \
    acc[(MB)+mb][NB] = __builtin_amdgcn_mfma_f32_32x32x16_bf16(                    \
        Aarr[mb][k16], Barr[k16], acc[(MB)+mb][NB], 0, 0, 0);                      \
  __builtin_amdgcn_s_setprio(0);

#define LD_A0(buf) _Pragma("unroll") for (int mb = 0; mb < 2; ++mb) \
    _Pragma("unroll") for (int k = 0; k < 4; ++k) { aM0[mb][k] = RDA32(buf, mb, k); }
#define LD_A1(buf) _Pragma("unroll") for (int mb = 0; mb < 2; ++mb) \
    _Pragma("unroll") for (int k = 0; k < 4; ++k) { aM1[mb][k] = RDA32(buf, mb+2, k); }
#define LD_B0(buf) _Pragma("unroll") for (int k = 0; k < 4; ++k) { bN0[k] = RDB32(buf, 0, k); }
#define LD_B1(buf) _Pragma("unroll") for (int k = 0; k < 4; ++k) { bN1[k] = RDB32(buf, 1, k); }

  // ---- prologue: T0 (4 halves, buf0) + T1 (A0,A1,B0, buf1); strict order ----
  STAGE(0,0,0); MEMF(); STAGE(0,0,1); MEMF(); STAGE(0,0,2); MEMF(); STAGE(0,0,3); MEMF();
  STAGE(1,1,0); MEMF(); STAGE(1,1,1); MEMF(); STAGE(1,1,2);
  VMCNT6(); BARM();    // T0's 8 loads landed -> buf0 ready; 6 in flight

  for (int it2 = 0; it2 < 8; ++it2) {
    const int t0 = it2 * 2;
    const bool nl = (it2 < 7);
    // ---- P1: rd aM0,bN0(buf0) ; MFMA M0N0 ----
    LD_A0(0); LD_B0(0);
    MEMF(); STAGE(1, t0+1, 3);
    BARM();
    MFMA_QUAD(0, aM0, 0, bN0);
    // ---- P2: rd aM1(buf0) ; MFMA M1N0 ----
    LD_A1(0);
    BARM();
    MFMA_QUAD(2, aM1, 0, bN0);
    // ---- P3: rd bN1(buf0) ; MFMA M0N1 ----
    LD_B1(0);
    if (nl) { MEMF(); STAGE(0, t0+2, 0); }
    BARM();
    MFMA_QUAD(0, aM0, 1, bN1);
    // ---- P4: publish buf1(t0+1) ; MFMA M1N1 ----
    if (nl) { MEMF(); STAGE(0, t0+2, 1); MEMF(); STAGE(0, t0+2, 2); VMCNT6(); }
    else    { VMCNT0(); }
    BARM();
    MFMA_QUAD(2, aM1, 1, bN1);
    // ---- P5: rd aM0,bN0(buf1) ; MFMA M0N0 ----
    LD_A0(1); LD_B0(1);
    if (nl) { MEMF(); STAGE(0, t0+2, 3); }
    BARM();
    MFMA_QUAD(0, aM0, 0, bN0);
    // ---- P6: rd aM1(buf1) ; MFMA M1N0 ----
    LD_A1(1);
    BARM();
    MFMA_QUAD(2, aM1, 0, bN0);
    // ---- P7: rd bN1(buf1) ; MFMA M0N1 ----
    LD_B1(1);
    if (nl) { MEMF(); STAGE(1, t0+3, 0); }
    BARM();
    MFMA_QUAD(0, aM0, 1, bN1);
    // ---- P8: publish buf0(t0+2) ; MFMA M1N1 ----
    if (nl) { MEMF(); STAGE(1, t0+3, 1); MEMF(); STAGE(1, t0+3, 2); VMCNT6(); }
    BARM();
    MFMA_QUAD(2, aM1, 1, bN1);
  }

  // ---- epilogue: two 128-row halves through LDS (vmcnt drained at it7 P4) ----
  // 32x32 C/D: col = colBase + (lane&31); row = mb*32 + (reg&3)+8*(reg>>2)+4*hi
  if (EPI == 0) {
    // layout [128][4][72]: row*288 + l*72 + (col>>2)
    bf16_t* C0 = (bf16_t*)smem;
    #pragma unroll
    for (int half = 0; half < 2; ++half) {
      BARM();
      if (wm == half) {
        const int lq = l31 & 3;            // l = col&3
        #pragma unroll
        for (int mb = 0; mb < 4; ++mb)
          #pragma unroll
          for (int nb = 0; nb < 2; ++nb) {
            const int colD4 = (wn * 64 + nb * 32 + l31) >> 2;
            #pragma unroll
            for (int reg = 0; reg < 16; ++reg) {
              const int row = mb * 32 + (reg & 3) + 8 * (reg >> 2) + 4 * hi;
              C0[row * 288 + lq * 72 + colD4] = (bf16_t)acc[mb][nb][reg];
            }
          }
      }
      BARM();
      #pragma unroll
      for (int i = 0; i < 8; ++i) {
        const int s = i * 512 + tid;            // 4096 16B segments
        const int row = s >> 5, l2 = (s >> 3) & 3, part = s & 7;
        bf16x8 v = *(const bf16x8*)&C0[row * 288 + l2 * 72 + part * 8];
        *(bf16x8*)&Outb[(brow0 + half * 128 + row) * 4096 +
                        l2 * 1024 + zi * 256 + nt * 64 + part * 8] = v;
      }
    }
  } else {
    bf16_t* C = (bf16_t*)smem;   // [128][264] padded
    #pragma unroll
    for (int half = 0; half < 2; ++half) {
      BARM();
      if (wm == half) {
        #pragma unroll
        for (int mb = 0; mb < 4; ++mb)
          #pragma unroll
          for (int nb = 0; nb < 2; ++nb) {
            const int col = wn * 64 + nb * 32 + l31;
            #pragma unroll
            for (int reg = 0; reg < 16; ++reg) {
              const int row = mb * 32 + (reg & 3) + 8 * (reg >> 2) + 4 * hi;
              C[row * 264 + col] = (bf16_t)acc[mb][nb][reg];
            }
          }
      }
      BARM();
      #pragma unroll
      for (int i = 0; i < 8; ++i) {
        const int s = i * 512 + tid;
        const int row = s >> 5, ch = s & 31;
        bf16x8 v = *(const bf16x8*)&C[row * 264 + ch * 8];
        *(bf16x8*)&Outb[(brow0 + half * 128 + row) * 4096 +
                        (size_t)zi * 1024 + ncol0 + ch * 8] = v;
      }
    }
  }
#undef RDA32
#undef RDB32
#undef MFMA_QUAD
#undef LD_A0
#undef LD_A1
#undef LD_B0
#undef LD_B1
#undef STAGE
}

// ---------------- P2 + bias: out[b, s*4+l] = o2[b,l,s] + bias ----------------
__global__ void permute_bias_kernel(const bf16_t* __restrict__ o2,
                                    const float* __restrict__ bias,
                                    float* __restrict__ out) {
  const int t = blockIdx.x * 256 + threadIdx.x;
  const int b = t >> 8;
  const int s0 = (t & 255) * 4;
  const size_t rowb = (size_t)b * 4096;
  bf16x4 vl[4];
  #pragma unroll
  for (int l = 0; l < 4; ++l) vl[l] = *(const bf16x4*)(o2 + rowb + l * 1024 + s0);
  #pragma unroll
  for (int si = 0; si < 4; ++si) {
    f32x4 bb = *(const f32x4*)(bias + (size_t)(s0 + si) * 4);
    f32x4 o;
    o[0] = (float)vl[0][si] + bb[0];
    o[1] = (float)vl[1][si] + bb[1];
    o[2] = (float)vl[2][si] + bb[2];
    o[3] = (float)vl[3][si] + bb[3];
    *(f32x4*)(out + rowb + (size_t)(s0 + si) * 4) = o;
  }
}

extern "C" void kernel_launch(void* const* d_in, const int* in_sizes, int n_in,
                              void* d_out, int out_size, void* d_ws, size_t ws_size,
                              hipStream_t stream) {
  const float* x    = (const float*)d_in[0];
  const float* w1   = (const float*)d_in[1];
  const float* w2   = (const float*)d_in[2];
  const float* bias = (const float*)d_in[3];
  float* out = (float*)d_out;

  char* ws = (char*)d_ws;
  const size_t xbBytes    = (size_t)B_DIM * 4096 * 2;   // 134 MB
  const size_t wBytes     = (size_t)8 << 20;            // per w array (bf16)
  bf16_t* xb    = (bf16_t*)(ws);
  bf16_t* w1b   = (bf16_t*)(ws + xbBytes);
  bf16_t* w2b   = (bf16_t*)(ws + xbBytes + wBytes);
  bf16_t* inter = (bf16_t*)(ws + xbBytes + 2 * wBytes);
  bf16_t* o2    = xb;   // xb dead after GEMM1; reuse for o2

  cast_all_kernel<<<36864, 256, 0, stream>>>(x, w1, w2, xb, w1b, w2b);
  monarch_gemm8<0><<<1024, 512, 0, stream>>>(xb, w1b, inter);
  monarch_gemm8<1><<<1024, 512, 0, stream>>>(inter, w2b, o2);
  permute_bias_kernel<<<16384, 256, 0, stream>>>(o2, bias, out);
}

// Round 12
// 471.713 us; speedup vs baseline: 1.2778x; 1.0746x over previous
//
#include <hip/hip_runtime.h>
#include <hip/hip_bf16.h>
#include <stdint.h>

typedef __bf16 bf16_t;
typedef bf16_t bf16x8 __attribute__((ext_vector_type(8)));
typedef bf16_t bf16x4 __attribute__((ext_vector_type(4)));
typedef float  f32x4  __attribute__((ext_vector_type(4)));

#define B_DIM 16384

// fenced barrier: reads/stages may not cross (they must issue pre-barrier)
#define BARM()   do { asm volatile("" ::: "memory"); \
                      __builtin_amdgcn_s_barrier();  \
                      asm volatile("" ::: "memory"); } while (0)
#define MEMF()   asm volatile("" ::: "memory")
#define VMCNT6() asm volatile("s_waitcnt vmcnt(6)" ::: "memory")
#define VMCNT0() asm volatile("s_waitcnt vmcnt(0)" ::: "memory")

// async global->LDS, 16B per lane; LDS dest is wave-uniform base (+lane*16 by HW)
__device__ __forceinline__ void async_copy16(void* lptr, const void* gptr) {
  __builtin_amdgcn_global_load_lds(
      (const __attribute__((address_space(1))) unsigned int*)gptr,
      (__attribute__((address_space(3))) unsigned int*)lptr, 16, 0, 0);
}

// ---------------- cast x + w1 + w2 fp32 -> bf16 ----------------
__global__ void cast_all_kernel(const float* __restrict__ x, const float* __restrict__ w1,
                                const float* __restrict__ w2, bf16_t* __restrict__ xb,
                                bf16_t* __restrict__ w1b, bf16_t* __restrict__ w2b) {
  size_t c = (size_t)blockIdx.x * 256 + threadIdx.x;  // 8-elem chunk id
  const float* s; bf16_t* d; size_t off;
  if (c < 8388608)      { s = x;  d = xb;  off = c; }            // 16384*4096/8
  else if (c < 8912896) { s = w1; d = w1b; off = c - 8388608; }  // 4*1024*1024/8
  else                  { s = w2; d = w2b; off = c - 8912896; }
  size_t i = off * 8;
  f32x4 a = *(const f32x4*)(s + i);
  f32x4 b = *(const f32x4*)(s + i + 4);
  bf16x8 o;
  o[0]=(bf16_t)a[0]; o[1]=(bf16_t)a[1]; o[2]=(bf16_t)a[2]; o[3]=(bf16_t)a[3];
  o[4]=(bf16_t)b[0]; o[5]=(bf16_t)b[1]; o[6]=(bf16_t)b[2]; o[7]=(bf16_t)b[3];
  *(bf16x8*)(d + i) = o;
}

// ============ 256x256 GEMM (BK=64, 8 waves, 16x16x32 bf16) ============
// 4 FAT PHASES per 2-K-tile iter (quad pairs share a B-frag); single barrier
// per phase: [reads(P); stage; (vmcnt gate); BAR; 32 MFMA].
// DMA issue order + vmcnt positions byte-identical to the verified R9 ledger:
//   Q1: rd aM0,bN0,aM1(buf0) | stage B1(t0+1)
//   Q2: rd bN1(buf0)         | stage A0,A1,B0(t0+2) | VM6 (publishes t0+1)
//   Q3: rd aM0,bN0,aM1(buf1) | stage B1(t0+2)
//   Q4: rd bN1(buf1)         | stage A0,A1,B0(t0+3) | VM6 (publishes t0+2)
// Stage->read distance 1 phase is safe: readers consume pre-BAR reads in
// MFMA before the barrier; stagers issue only after crossing it.
// EPI 0: P1-scatter -> inter[b*4096 + l*1024 + r]      (GEMM1)
// EPI 1: contiguous -> o2[b*4096 + zi*1024 + s]        (GEMM2)
template<int EPI>
__global__ __launch_bounds__(512, 2)
void monarch_gemm8(const bf16_t* __restrict__ Ab, const bf16_t* __restrict__ Wb,
                   bf16_t* __restrict__ Outb)
{
  __shared__ __align__(16) char smem[131072];
  const int tid  = threadIdx.x;
  const int lane = tid & 63;
  const int wid  = tid >> 6;
  const int wm   = wid >> 2;       // 2 (M) x 4 (N) wave grid; wave tile 128x64
  const int wn   = wid & 3;

  // XCD-chunked swizzle: 1024 blocks, 128 consecutive logicals per XCD
  const int pb = blockIdx.x;
  const int lb = (pb & 7) * 128 + (pb >> 3);
  const int zi = lb >> 8;                  // k (GEMM1) or l (GEMM2)
  const int mt = (lb & 255) >> 2;          // 64 M-tiles
  const int nt = lb & 3;                   // 4 N-tiles

  const size_t brow0 = (size_t)mt * 256;
  const int    ncol0 = nt * 256;

  const bf16_t* Asrc = Ab + brow0 * 4096 + (size_t)zi * 1024;          // stride 4096
  const bf16_t* Bsrc = Wb + ((size_t)zi << 20) + (size_t)ncol0 * 1024; // stride 1024

  // staging source swizzle (T2): linear LDS chunk c' holds source chunk c'^(row&7)
  const int sRow = lane >> 3;
  const int sC   = (lane & 7) ^ sRow;

// stage half H (0=A0,1=A1,2=B0,3=B1) of K-tile T into buffer BUF (literals!)
#define STAGE(BUF, T, H) do {                                                   \
    const bf16_t* _s = (H) < 2 ? Asrc + ((size_t)((H) * 128) * 4096) + (T) * 64 \
                               : Bsrc + ((size_t)(((H)-2) * 128) * 1024) + (T) * 64; \
    const size_t _st = (H) < 2 ? 4096 : 1024;                                   \
    async_copy16(smem + (BUF)*65536 + ((H)>>1)*32768 + ((H)&1)*16384 + wid*1024,\
                 _s + (size_t)(wid * 8 + sRow) * _st + sC * 8);                 \
    async_copy16(smem + (BUF)*65536 + ((H)>>1)*32768 + ((H)&1)*16384 + 8192 + wid*1024, \
                 _s + (size_t)(64 + wid * 8 + sRow) * _st + sC * 8);            \
  } while (0)

  // ds_read addressing (swizzled): chunk c0 read at linear c0^(lane&7)
  const int cs0 = ((0 + (lane >> 4)) ^ (lane & 7)) * 16;   // kk=0
  const int cs1 = ((4 + (lane >> 4)) ^ (lane & 7)) * 16;   // kk=1
  const int aBase = (wm * 128 + (lane & 15)) * 128;
  const int bBase = 32768 + (wn * 64 + (lane & 15)) * 128;

#define RDA(buf, m, kk) (*(const bf16x8*)(smem + (buf)*65536 + aBase + (m)*2048 + ((kk)?cs1:cs0)))
#define RDB(buf, n, kk) (*(const bf16x8*)(smem + (buf)*65536 + bBase + (n)*2048 + ((kk)?cs1:cs0)))

  f32x4 acc[8][4] = {};
  bf16x8 aM0[4][2], aM1[4][2], bN0[2][2], bN1[2][2];

#define MFMA_QUAD(AR, Aarr, NB, Barr)                                              \
  _Pragma("unroll") for (int m = 0; m < 4; ++m)                                    \
  _Pragma("unroll") for (int n = 0; n < 2; ++n)                                    \
  _Pragma("unroll") for (int kk = 0; kk < 2; ++kk)                                 \
    acc[(AR)+m][(NB)+n] = __builtin_amdgcn_mfma_f32_16x16x32_bf16(                 \
        Aarr[m][kk], Barr[n][kk], acc[(AR)+m][(NB)+n], 0, 0, 0);

#define LD_A0(buf) _Pragma("unroll") for (int m = 0; m < 4; ++m) { \
    aM0[m][0] = RDA(buf,m,0); aM0[m][1] = RDA(buf,m,1); }
#define LD_A1(buf) _Pragma("unroll") for (int m = 0; m < 4; ++m) { \
    aM1[m][0] = RDA(buf,m+4,0); aM1[m][1] = RDA(buf,m+4,1); }
#define LD_B0(buf) _Pragma("unroll") for (int n = 0; n < 2; ++n) { \
    bN0[n][0] = RDB(buf,n,0); bN0[n][1] = RDB(buf,n,1); }
#define LD_B1(buf) _Pragma("unroll") for (int n = 0; n < 2; ++n) { \
    bN1[n][0] = RDB(buf,n+2,0); bN1[n][1] = RDB(buf,n+2,1); }

  // ---- prologue: T0 (4 halves, buf0) + T1 (A0,A1,B0, buf1); strict order ----
  STAGE(0,0,0); MEMF(); STAGE(0,0,1); MEMF(); STAGE(0,0,2); MEMF(); STAGE(0,0,3); MEMF();
  STAGE(1,1,0); MEMF(); STAGE(1,1,1); MEMF(); STAGE(1,1,2);
  VMCNT6(); BARM();    // T0's 8 loads landed -> buf0 ready; 6 in flight

  for (int it2 = 0; it2 < 8; ++it2) {
    const int t0 = it2 * 2;
    const bool nl = (it2 < 7);
    // ---- Q1: rd aM0,bN0,aM1(buf0) ; MFMA {M0,M1}xN0 ----
    LD_A0(0); LD_B0(0); LD_A1(0);
    MEMF(); STAGE(1, t0+1, 3);
    BARM();
    __builtin_amdgcn_s_setprio(1);
    MFMA_QUAD(0, aM0, 0, bN0);
    MFMA_QUAD(4, aM1, 0, bN0);
    __builtin_amdgcn_s_setprio(0);
    // ---- Q2: rd bN1(buf0) ; stages + publish t0+1 ; MFMA {M0,M1}xN1 ----
    LD_B1(0);
    if (nl) { MEMF(); STAGE(0, t0+2, 0); MEMF(); STAGE(0, t0+2, 1);
              MEMF(); STAGE(0, t0+2, 2); VMCNT6(); }
    else    { VMCNT0(); }
    BARM();
    __builtin_amdgcn_s_setprio(1);
    MFMA_QUAD(0, aM0, 2, bN1);
    MFMA_QUAD(4, aM1, 2, bN1);
    __builtin_amdgcn_s_setprio(0);
    // ---- Q3: rd aM0,bN0,aM1(buf1) ; MFMA {M0,M1}xN0 ----
    LD_A0(1); LD_B0(1); LD_A1(1);
    if (nl) { MEMF(); STAGE(0, t0+2, 3); }
    BARM();
    __builtin_amdgcn_s_setprio(1);
    MFMA_QUAD(0, aM0, 0, bN0);
    MFMA_QUAD(4, aM1, 0, bN0);
    __builtin_amdgcn_s_setprio(0);
    // ---- Q4: rd bN1(buf1) ; stages + publish t0+2 ; MFMA {M0,M1}xN1 ----
    LD_B1(1);
    if (nl) { MEMF(); STAGE(1, t0+3, 0); MEMF(); STAGE(1, t0+3, 1);
              MEMF(); STAGE(1, t0+3, 2); VMCNT6(); }
    BARM();
    __builtin_amdgcn_s_setprio(1);
    MFMA_QUAD(0, aM0, 2, bN1);
    MFMA_QUAD(4, aM1, 2, bN1);
    __builtin_amdgcn_s_setprio(0);
  }

  // ---- epilogue: two 128-row halves through LDS (vmcnt drained at it7 Q2) ----
  if (EPI == 0) {
    // layout [128][4][72]: row*288 + l*72 + rv
    bf16_t* C0 = (bf16_t*)smem;
    #pragma unroll
    for (int half = 0; half < 2; ++half) {
      BARM();
      if (wm == half) {
        const int rg = lane >> 4, cl = lane & 15;
        const int l = cl & 3, rvb = cl >> 2;
        #pragma unroll
        for (int m = 0; m < 8; ++m)
          #pragma unroll
          for (int n = 0; n < 4; ++n) {
            const int rowb = (m * 16 + rg * 4) * 288 + l * 72 + wn * 16 + n * 4 + rvb;
            #pragma unroll
            for (int j = 0; j < 4; ++j)
              C0[rowb + j * 288] = (bf16_t)acc[m][n][j];
          }
      }
      BARM();
      #pragma unroll
      for (int i = 0; i < 8; ++i) {
        const int s = i * 512 + tid;            // 4096 16B segments
        const int row = s >> 5, l2 = (s >> 3) & 3, part = s & 7;
        bf16x8 v = *(const bf16x8*)&C0[row * 288 + l2 * 72 + part * 8];
        *(bf16x8*)&Outb[(brow0 + half * 128 + row) * 4096 +
                        l2 * 1024 + zi * 256 + nt * 64 + part * 8] = v;
      }
    }
  } else {
    bf16_t* C = (bf16_t*)smem;   // [128][264] padded
    #pragma unroll
    for (int half = 0; half < 2; ++half) {
      BARM();
      if (wm == half) {
        const int rg = lane >> 4, cl = lane & 15;
        #pragma unroll
        for (int m = 0; m < 8; ++m)
          #pragma unroll
          for (int n = 0; n < 4; ++n) {
            const int rl = m * 16 + rg * 4;
            const int col = wn * 64 + n * 16 + cl;
            #pragma unroll
            for (int j = 0; j < 4; ++j)
              C[(rl + j) * 264 + col] = (bf16_t)acc[m][n][j];
          }
      }
      BARM();
      #pragma unroll
      for (int i = 0; i < 8; ++i) {
        const int s = i * 512 + tid;
        const int row = s >> 5, ch = s & 31;
        bf16x8 v = *(const bf16x8*)&C[row * 264 + ch * 8];
        *(bf16x8*)&Outb[(brow0 + half * 128 + row) * 4096 +
                        (size_t)zi * 1024 + ncol0 + ch * 8] = v;
      }
    }
  }
#undef RDA
#undef RDB
#undef MFMA_QUAD
#undef LD_A0
#undef LD_A1
#undef LD_B0
#undef LD_B1
#undef STAGE
}

// ---------------- P2 + bias: out[b, s*4+l] = o2[b,l,s] + bias ----------------
__global__ void permute_bias_kernel(const bf16_t* __restrict__ o2,
                                    const float* __restrict__ bias,
                                    float* __restrict__ out) {
  const int t = blockIdx.x * 256 + threadIdx.x;
  const int b = t >> 8;
  const int s0 = (t & 255) * 4;
  const size_t rowb = (size_t)b * 4096;
  bf16x4 vl[4];
  #pragma unroll
  for (int l = 0; l < 4; ++l) vl[l] = *(const bf16x4*)(o2 + rowb + l * 1024 + s0);
  #pragma unroll
  for (int si = 0; si < 4; ++si) {
    f32x4 bb = *(const f32x4*)(bias + (size_t)(s0 + si) * 4);
    f32x4 o;
    o[0] = (float)vl[0][si] + bb[0];
    o[1] = (float)vl[1][si] + bb[1];
    o[2] = (float)vl[2][si] + bb[2];
    o[3] = (float)vl[3][si] + bb[3];
    *(f32x4*)(out + rowb + (size_t)(s0 + si) * 4) = o;
  }
}

extern "C" void kernel_launch(void* const* d_in, const int* in_sizes, int n_in,
                              void* d_out, int out_size, void* d_ws, size_t ws_size,
                              hipStream_t stream) {
  const float* x    = (const float*)d_in[0];
  const float* w1   = (const float*)d_in[1];
  const float* w2   = (const float*)d_in[2];
  const float* bias = (const float*)d_in[3];
  float* out = (float*)d_out;

  char* ws = (char*)d_ws;
  const size_t xbBytes    = (size_t)B_DIM * 4096 * 2;   // 134 MB
  const size_t wBytes     = (size_t)8 << 20;            // per w array (bf16)
  bf16_t* xb    = (bf16_t*)(ws);
  bf16_t* w1b   = (bf16_t*)(ws + xbBytes);
  bf16_t* w2b   = (bf16_t*)(ws + xbBytes + wBytes);
  bf16_t* inter = (bf16_t*)(ws + xbBytes + 2 * wBytes);
  bf16_t* o2    = xb;   // xb dead after GEMM1; reuse for o2

  cast_all_kernel<<<36864, 256, 0, stream>>>(x, w1, w2, xb, w1b, w2b);
  monarch_gemm8<0><<<1024, 512, 0, stream>>>(xb, w1b, inter);
  monarch_gemm8<1><<<1024, 512, 0, stream>>>(inter, w2b, o2);
  permute_bias_kernel<<<16384, 256, 0, stream>>>(o2, bias, out);
}

// Round 13
// 462.331 us; speedup vs baseline: 1.3037x; 1.0203x over previous
//
#include <hip/hip_runtime.h>
#include <hip/hip_bf16.h>
#include <stdint.h>

typedef __bf16 bf16_t;
typedef bf16_t bf16x8 __attribute__((ext_vector_type(8)));
typedef bf16_t bf16x4 __attribute__((ext_vector_type(4)));
typedef float  f32x4  __attribute__((ext_vector_type(4)));

#define B_DIM 16384

// fenced barrier: reads/stages may not cross (they must issue pre-barrier)
#define BARM()   do { asm volatile("" ::: "memory"); \
                      __builtin_amdgcn_s_barrier();  \
                      asm volatile("" ::: "memory"); } while (0)
#define MEMF()   asm volatile("" ::: "memory")
#define VMCNT6() asm volatile("s_waitcnt vmcnt(6)" ::: "memory")
#define VMCNT0() asm volatile("s_waitcnt vmcnt(0)" ::: "memory")

// async global->LDS, 16B per lane; LDS dest is wave-uniform base (+lane*16 by HW)
__device__ __forceinline__ void async_copy16(void* lptr, const void* gptr) {
  __builtin_amdgcn_global_load_lds(
      (const __attribute__((address_space(1))) unsigned int*)gptr,
      (__attribute__((address_space(3))) unsigned int*)lptr, 16, 0, 0);
}

// ---------------- cast x + w1 + w2 fp32 -> bf16 ----------------
__global__ void cast_all_kernel(const float* __restrict__ x, const float* __restrict__ w1,
                                const float* __restrict__ w2, bf16_t* __restrict__ xb,
                                bf16_t* __restrict__ w1b, bf16_t* __restrict__ w2b) {
  size_t c = (size_t)blockIdx.x * 256 + threadIdx.x;  // 8-elem chunk id
  const float* s; bf16_t* d; size_t off;
  if (c < 8388608)      { s = x;  d = xb;  off = c; }            // 16384*4096/8
  else if (c < 8912896) { s = w1; d = w1b; off = c - 8388608; }  // 4*1024*1024/8
  else                  { s = w2; d = w2b; off = c - 8912896; }
  size_t i = off * 8;
  f32x4 a = *(const f32x4*)(s + i);
  f32x4 b = *(const f32x4*)(s + i + 4);
  bf16x8 o;
  o[0]=(bf16_t)a[0]; o[1]=(bf16_t)a[1]; o[2]=(bf16_t)a[2]; o[3]=(bf16_t)a[3];
  o[4]=(bf16_t)b[0]; o[5]=(bf16_t)b[1]; o[6]=(bf16_t)b[2]; o[7]=(bf16_t)b[3];
  *(bf16x8*)(d + i) = o;
}

// ============ 256x256 GEMM (BK=64, 8 waves, 16x16x32 bf16) ============
// 4 FAT PHASES per 2-K-tile iter (quad pairs share a B-frag); single barrier
// per phase: [reads(P); stage; (vmcnt gate); BAR; 32 MFMA].  (R12, best-known)
//   Q1: rd aM0,bN0,aM1(buf0) | stage B1(t0+1)
//   Q2: rd bN1(buf0)         | stage A0,A1,B0(t0+2) | VM6 (publishes t0+1)
//   Q3: rd aM0,bN0,aM1(buf1) | stage B1(t0+2)
//   Q4: rd bN1(buf1)         | stage A0,A1,B0(t0+3) | VM6 (publishes t0+2)
// EPI 0: P1-scatter -> inter[b*4096 + l*1024 + r]      (GEMM1)
// EPI 1: contiguous -> o2[b*4096 + zi*1024 + s]        (GEMM2)
template<int EPI>
__global__ __launch_bounds__(512, 2)
void monarch_gemm8(const bf16_t* __restrict__ Ab, const bf16_t* __restrict__ Wb,
                   bf16_t* __restrict__ Outb)
{
  __shared__ __align__(16) char smem[131072];
  const int tid  = threadIdx.x;
  const int lane = tid & 63;
  const int wid  = tid >> 6;
  const int wm   = wid >> 2;       // 2 (M) x 4 (N) wave grid; wave tile 128x64
  const int wn   = wid & 3;

  // XCD-chunked swizzle: 1024 blocks, 128 consecutive logicals per XCD
  const int pb = blockIdx.x;
  const int lb = (pb & 7) * 128 + (pb >> 3);
  const int zi = lb >> 8;                  // k (GEMM1) or l (GEMM2)
  const int mt = (lb & 255) >> 2;          // 64 M-tiles
  const int nt = lb & 3;                   // 4 N-tiles

  const size_t brow0 = (size_t)mt * 256;
  const int    ncol0 = nt * 256;

  const bf16_t* Asrc = Ab + brow0 * 4096 + (size_t)zi * 1024;          // stride 4096
  const bf16_t* Bsrc = Wb + ((size_t)zi << 20) + (size_t)ncol0 * 1024; // stride 1024

  // staging source swizzle (T2): linear LDS chunk c' holds source chunk c'^(row&7)
  const int sRow = lane >> 3;
  const int sC   = (lane & 7) ^ sRow;

// stage half H (0=A0,1=A1,2=B0,3=B1) of K-tile T into buffer BUF (literals!)
#define STAGE(BUF, T, H) do {                                                   \
    const bf16_t* _s = (H) < 2 ? Asrc + ((size_t)((H) * 128) * 4096) + (T) * 64 \
                               : Bsrc + ((size_t)(((H)-2) * 128) * 1024) + (T) * 64; \
    const size_t _st = (H) < 2 ? 4096 : 1024;                                   \
    async_copy16(smem + (BUF)*65536 + ((H)>>1)*32768 + ((H)&1)*16384 + wid*1024,\
                 _s + (size_t)(wid * 8 + sRow) * _st + sC * 8);                 \
    async_copy16(smem + (BUF)*65536 + ((H)>>1)*32768 + ((H)&1)*16384 + 8192 + wid*1024, \
                 _s + (size_t)(64 + wid * 8 + sRow) * _st + sC * 8);            \
  } while (0)

  // ds_read addressing (swizzled): chunk c0 read at linear c0^(lane&7)
  const int cs0 = ((0 + (lane >> 4)) ^ (lane & 7)) * 16;   // kk=0
  const int cs1 = ((4 + (lane >> 4)) ^ (lane & 7)) * 16;   // kk=1
  const int aBase = (wm * 128 + (lane & 15)) * 128;
  const int bBase = 32768 + (wn * 64 + (lane & 15)) * 128;

#define RDA(buf, m, kk) (*(const bf16x8*)(smem + (buf)*65536 + aBase + (m)*2048 + ((kk)?cs1:cs0)))
#define RDB(buf, n, kk) (*(const bf16x8*)(smem + (buf)*65536 + bBase + (n)*2048 + ((kk)?cs1:cs0)))

  f32x4 acc[8][4] = {};
  bf16x8 aM0[4][2], aM1[4][2], bN0[2][2], bN1[2][2];

#define MFMA_QUAD(AR, Aarr, NB, Barr)                                              \
  _Pragma("unroll") for (int m = 0; m < 4; ++m)                                    \
  _Pragma("unroll") for (int n = 0; n < 2; ++n)                                    \
  _Pragma("unroll") for (int kk = 0; kk < 2; ++kk)                                 \
    acc[(AR)+m][(NB)+n] = __builtin_amdgcn_mfma_f32_16x16x32_bf16(                 \
        Aarr[m][kk], Barr[n][kk], acc[(AR)+m][(NB)+n], 0, 0, 0);

#define LD_A0(buf) _Pragma("unroll") for (int m = 0; m < 4; ++m) { \
    aM0[m][0] = RDA(buf,m,0); aM0[m][1] = RDA(buf,m,1); }
#define LD_A1(buf) _Pragma("unroll") for (int m = 0; m < 4; ++m) { \
    aM1[m][0] = RDA(buf,m+4,0); aM1[m][1] = RDA(buf,m+4,1); }
#define LD_B0(buf) _Pragma("unroll") for (int n = 0; n < 2; ++n) { \
    bN0[n][0] = RDB(buf,n,0); bN0[n][1] = RDB(buf,n,1); }
#define LD_B1(buf) _Pragma("unroll") for (int n = 0; n < 2; ++n) { \
    bN1[n][0] = RDB(buf,n+2,0); bN1[n][1] = RDB(buf,n+2,1); }

  // ---- prologue: T0 (4 halves, buf0) + T1 (A0,A1,B0, buf1); strict order ----
  STAGE(0,0,0); MEMF(); STAGE(0,0,1); MEMF(); STAGE(0,0,2); MEMF(); STAGE(0,0,3); MEMF();
  STAGE(1,1,0); MEMF(); STAGE(1,1,1); MEMF(); STAGE(1,1,2);
  VMCNT6(); BARM();    // T0's 8 loads landed -> buf0 ready; 6 in flight

  for (int it2 = 0; it2 < 8; ++it2) {
    const int t0 = it2 * 2;
    const bool nl = (it2 < 7);
    // ---- Q1: rd aM0,bN0,aM1(buf0) ; MFMA {M0,M1}xN0 ----
    LD_A0(0); LD_B0(0); LD_A1(0);
    MEMF(); STAGE(1, t0+1, 3);
    BARM();
    __builtin_amdgcn_s_setprio(1);
    MFMA_QUAD(0, aM0, 0, bN0);
    MFMA_QUAD(4, aM1, 0, bN0);
    __builtin_amdgcn_s_setprio(0);
    // ---- Q2: rd bN1(buf0) ; stages + publish t0+1 ; MFMA {M0,M1}xN1 ----
    LD_B1(0);
    if (nl) { MEMF(); STAGE(0, t0+2, 0); MEMF(); STAGE(0, t0+2, 1);
              MEMF(); STAGE(0, t0+2, 2); VMCNT6(); }
    else    { VMCNT0(); }
    BARM();
    __builtin_amdgcn_s_setprio(1);
    MFMA_QUAD(0, aM0, 2, bN1);
    MFMA_QUAD(4, aM1, 2, bN1);
    __builtin_amdgcn_s_setprio(0);
    // ---- Q3: rd aM0,bN0,aM1(buf1) ; MFMA {M0,M1}xN0 ----
    LD_A0(1); LD_B0(1); LD_A1(1);
    if (nl) { MEMF(); STAGE(0, t0+2, 3); }
    BARM();
    __builtin_amdgcn_s_setprio(1);
    MFMA_QUAD(0, aM0, 0, bN0);
    MFMA_QUAD(4, aM1, 0, bN0);
    __builtin_amdgcn_s_setprio(0);
    // ---- Q4: rd bN1(buf1) ; stages + publish t0+2 ; MFMA {M0,M1}xN1 ----
    LD_B1(1);
    if (nl) { MEMF(); STAGE(1, t0+3, 0); MEMF(); STAGE(1, t0+3, 1);
              MEMF(); STAGE(1, t0+3, 2); VMCNT6(); }
    BARM();
    __builtin_amdgcn_s_setprio(1);
    MFMA_QUAD(0, aM0, 2, bN1);
    MFMA_QUAD(4, aM1, 2, bN1);
    __builtin_amdgcn_s_setprio(0);
  }

  // ---- epilogue: two 128-row halves through LDS (vmcnt drained at it7 Q2) ----
  if (EPI == 0) {
    // layout [128][4][72]: row*288 + l*72 + rv
    bf16_t* C0 = (bf16_t*)smem;
    #pragma unroll
    for (int half = 0; half < 2; ++half) {
      BARM();
      if (wm == half) {
        const int rg = lane >> 4, cl = lane & 15;
        const int l = cl & 3, rvb = cl >> 2;
        #pragma unroll
        for (int m = 0; m < 8; ++m)
          #pragma unroll
          for (int n = 0; n < 4; ++n) {
            const int rowb = (m * 16 + rg * 4) * 288 + l * 72 + wn * 16 + n * 4 + rvb;
            #pragma unroll
            for (int j = 0; j < 4; ++j)
              C0[rowb + j * 288] = (bf16_t)acc[m][n][j];
          }
      }
      BARM();
      #pragma unroll
      for (int i = 0; i < 8; ++i) {
        const int s = i * 512 + tid;            // 4096 16B segments
        const int row = s >> 5, l2 = (s >> 3) & 3, part = s & 7;
        bf16x8 v = *(const bf16x8*)&C0[row * 288 + l2 * 72 + part * 8];
        *(bf16x8*)&Outb[(brow0 + half * 128 + row) * 4096 +
                        l2 * 1024 + zi * 256 + nt * 64 + part * 8] = v;
      }
    }
  } else {
    bf16_t* C = (bf16_t*)smem;   // [128][264] padded
    #pragma unroll
    for (int half = 0; half < 2; ++half) {
      BARM();
      if (wm == half) {
        const int rg = lane >> 4, cl = lane & 15;
        #pragma unroll
        for (int m = 0; m < 8; ++m)
          #pragma unroll
          for (int n = 0; n < 4; ++n) {
            const int rl = m * 16 + rg * 4;
            const int col = wn * 64 + n * 16 + cl;
            #pragma unroll
            for (int j = 0; j < 4; ++j)
              C[(rl + j) * 264 + col] = (bf16_t)acc[m][n][j];
          }
      }
      BARM();
      #pragma unroll
      for (int i = 0; i < 8; ++i) {
        const int s = i * 512 + tid;
        const int row = s >> 5, ch = s & 31;
        bf16x8 v = *(const bf16x8*)&C[row * 264 + ch * 8];
        *(bf16x8*)&Outb[(brow0 + half * 128 + row) * 4096 +
                        (size_t)zi * 1024 + ncol0 + ch * 8] = v;
      }
    }
  }
#undef RDA
#undef RDB
#undef MFMA_QUAD
#undef LD_A0
#undef LD_A1
#undef LD_B0
#undef LD_B1
#undef STAGE
}

// -------- P2 + bias: out[b, s*4+l] = o2[b,l,s] + bias  (16B-load version) ----
// thread handles s0..s0+7 for one b-row: 4x bf16x8 loads (16B), 8x f32x4 stores
__global__ void permute_bias_kernel(const bf16_t* __restrict__ o2,
                                    const float* __restrict__ bias,
                                    float* __restrict__ out) {
  const int t = blockIdx.x * 256 + threadIdx.x;
  const int b = t >> 7;
  const int s0 = (t & 127) * 8;
  const size_t rowb = (size_t)b * 4096;
  bf16x8 vl[4];
  #pragma unroll
  for (int l = 0; l < 4; ++l) vl[l] = *(const bf16x8*)(o2 + rowb + l * 1024 + s0);
  #pragma unroll
  for (int si = 0; si < 8; ++si) {
    f32x4 bb = *(const f32x4*)(bias + (size_t)(s0 + si) * 4);
    f32x4 o;
    o[0] = (float)vl[0][si] + bb[0];
    o[1] = (float)vl[1][si] + bb[1];
    o[2] = (float)vl[2][si] + bb[2];
    o[3] = (float)vl[3][si] + bb[3];
    *(f32x4*)(out + rowb + (size_t)(s0 + si) * 4) = o;
  }
}

extern "C" void kernel_launch(void* const* d_in, const int* in_sizes, int n_in,
                              void* d_out, int out_size, void* d_ws, size_t ws_size,
                              hipStream_t stream) {
  const float* x    = (const float*)d_in[0];
  const float* w1   = (const float*)d_in[1];
  const float* w2   = (const float*)d_in[2];
  const float* bias = (const float*)d_in[3];
  float* out = (float*)d_out;

  char* ws = (char*)d_ws;
  const size_t xbBytes    = (size_t)B_DIM * 4096 * 2;   // 134 MB
  const size_t wBytes     = (size_t)8 << 20;            // per w array (bf16)
  bf16_t* xb    = (bf16_t*)(ws);
  bf16_t* w1b   = (bf16_t*)(ws + xbBytes);
  bf16_t* w2b   = (bf16_t*)(ws + xbBytes + wBytes);
  bf16_t* inter = (bf16_t*)(ws + xbBytes + 2 * wBytes);
  bf16_t* o2    = xb;   // xb dead after GEMM1; reuse for o2

  cast_all_kernel<<<36864, 256, 0, stream>>>(x, w1, w2, xb, w1b, w2b);
  monarch_gemm8<0><<<1024, 512, 0, stream>>>(xb, w1b, inter);
  monarch_gemm8<1><<<1024, 512, 0, stream>>>(inter, w2b, o2);
  permute_bias_kernel<<<8192, 256, 0, stream>>>(o2, bias, out);
}